// Round 1
// baseline (1421.174 us; speedup 1.0000x reference)
//
#include <hip/hip_runtime.h>
#include <hip/hip_bf16.h>

#define DD 1024
#define NHD 64
#define NHEAD 16
#define NE 8
#define NT 4096
#define SS 2048

typedef float v4f __attribute__((ext_vector_type(4)));
typedef short bfx8 __attribute__((ext_vector_type(8)));
typedef float fx4 __attribute__((ext_vector_type(4)));

__device__ inline ushort f2bf(float f) {
  union { float f; unsigned u; } x; x.f = f;
  unsigned r = (x.u + 0x7FFFu + ((x.u >> 16) & 1u)) >> 16;
  return (ushort)r;
}

// ---------------- RMSNorm: one block per row ----------------
__global__ __launch_bounds__(256) void k_rmsnorm(
    const float* __restrict__ x, const float* __restrict__ w,
    float* __restrict__ of32, ushort* __restrict__ obf) {
  int row = blockIdx.x;
  int tid = threadIdx.x;
  v4f v = *(const v4f*)(x + (size_t)row * DD + tid * 4);
  float ss = v[0]*v[0] + v[1]*v[1] + v[2]*v[2] + v[3]*v[3];
  #pragma unroll
  for (int o = 32; o; o >>= 1) ss += __shfl_down(ss, o);
  __shared__ float red[4];
  if ((tid & 63) == 0) red[tid >> 6] = ss;
  __syncthreads();
  float tot = red[0] + red[1] + red[2] + red[3];
  float sc = rsqrtf(tot * (1.0f / DD) + 1e-5f);
  v4f wv = *(const v4f*)(w + tid * 4);
  v4f o;
  o[0] = v[0]*sc*wv[0]; o[1] = v[1]*sc*wv[1];
  o[2] = v[2]*sc*wv[2]; o[3] = v[3]*sc*wv[3];
  if (of32) *(v4f*)(of32 + (size_t)row * DD + tid * 4) = o;
  if (obf) {
    ushort4 ub;
    ub.x = f2bf(o[0]); ub.y = f2bf(o[1]); ub.z = f2bf(o[2]); ub.w = f2bf(o[3]);
    *(ushort4*)(obf + (size_t)row * DD + tid * 4) = ub;
  }
}

// ---------------- fp32 GEMM: C = A[M,K] @ B[K,N] (B row-major) ----------------
// MODE 0: z-select among (B0,C0)/(B1,C1)/(B2,C2).  MODE 1: C0 = A@B0 + resid.
// 64x64 tile, BK=32, 256 threads, 4x4 per thread. K,M,N multiples of 32/64.
template<int MODE>
__global__ __launch_bounds__(256) void k_gemm_f32(
    const float* __restrict__ A,
    const float* __restrict__ B0, const float* __restrict__ B1, const float* __restrict__ B2,
    float* __restrict__ C0, float* __restrict__ C1, float* __restrict__ C2,
    const float* __restrict__ resid, int M, int N, int K) {
  const float* B = (blockIdx.z == 0) ? B0 : (blockIdx.z == 1) ? B1 : B2;
  float* C = (blockIdx.z == 0) ? C0 : (blockIdx.z == 1) ? C1 : C2;
  __shared__ float At[32][64];   // transposed A tile: At[k][m]
  __shared__ float Bs[32][64];   // Bs[k][n]
  int tid = threadIdx.x;
  int m0 = blockIdx.x * 64, n0 = blockIdx.y * 64;
  int r0 = (tid >> 4) << 2, c0 = (tid & 15) << 2;
  float acc[4][4] = {};
  int ar = tid >> 3, akq = (tid & 7) << 2;       // A: 64 rows x 8 quad-chunks
  int bk = tid >> 4, bn = (tid & 15) << 2;       // B: 32 rows x 16 quad-chunks
  for (int kt = 0; kt < K; kt += 32) {
    v4f a0 = *(const v4f*)(A + (size_t)(m0 + ar) * K + kt + akq);
    v4f a1 = *(const v4f*)(A + (size_t)(m0 + ar + 32) * K + kt + akq);
    v4f b0 = *(const v4f*)(B + (size_t)(kt + bk) * N + n0 + bn);
    v4f b1 = *(const v4f*)(B + (size_t)(kt + bk + 16) * N + n0 + bn);
    __syncthreads();
    At[akq+0][ar] = a0[0]; At[akq+1][ar] = a0[1]; At[akq+2][ar] = a0[2]; At[akq+3][ar] = a0[3];
    At[akq+0][ar+32] = a1[0]; At[akq+1][ar+32] = a1[1]; At[akq+2][ar+32] = a1[2]; At[akq+3][ar+32] = a1[3];
    *(v4f*)&Bs[bk][bn] = b0;
    *(v4f*)&Bs[bk + 16][bn] = b1;
    __syncthreads();
    #pragma unroll
    for (int k = 0; k < 32; ++k) {
      v4f a = *(v4f*)&At[k][r0];
      v4f b = *(v4f*)&Bs[k][c0];
      #pragma unroll
      for (int i = 0; i < 4; ++i)
        #pragma unroll
        for (int j = 0; j < 4; ++j)
          acc[i][j] = fmaf(a[i], b[j], acc[i][j]);
    }
  }
  #pragma unroll
  for (int i = 0; i < 4; ++i) {
    size_t idx = (size_t)(m0 + r0 + i) * N + n0 + c0;
    v4f o;
    o[0] = acc[i][0]; o[1] = acc[i][1]; o[2] = acc[i][2]; o[3] = acc[i][3];
    if (MODE == 1) {
      v4f rz = *(const v4f*)(resid + idx);
      o[0] += rz[0]; o[1] += rz[1]; o[2] += rz[2]; o[3] += rz[3];
    }
    *(v4f*)(C + idx) = o;
  }
}

// ---------------- fp32 flash attention (causal) ----------------
// block = (q-tile of 64 rows) x (b,h). 256 threads, 4x4 per thread.
__global__ __launch_bounds__(256) void k_attn(
    const float* __restrict__ q, const float* __restrict__ k,
    const float* __restrict__ v, float* __restrict__ aout) {
  int qi = 31 - (int)blockIdx.x;          // heavy tiles first
  int bh = blockIdx.y;
  int b = bh >> 4, h = bh & 15;
  int q0 = qi * 64;
  int tokq = b * SS + q0;
  int cb = h * NHD;
  __shared__ float Qt[64][64];   // Qt[k][row], pre-scaled by 1/sqrt(64)
  __shared__ float KP[64][64];   // Kt[k][col] then reused as Pt[k][row]
  __shared__ float Vs[64][64];   // Vs[k][d]
  int tid = threadIdx.x;
  int r0 = (tid >> 4) << 2, c0 = (tid & 15) << 2;
  #pragma unroll
  for (int it = 0; it < 4; ++it) {
    int lin = it * 256 + tid;
    int r = lin >> 4, kq = (lin & 15) << 2;
    v4f qv = *(const v4f*)(q + (size_t)(tokq + r) * DD + cb + kq);
    Qt[kq+0][r] = qv[0]*0.125f; Qt[kq+1][r] = qv[1]*0.125f;
    Qt[kq+2][r] = qv[2]*0.125f; Qt[kq+3][r] = qv[3]*0.125f;
  }
  float m[4], l[4], O[4][4];
  #pragma unroll
  for (int i = 0; i < 4; ++i) {
    m[i] = -1e30f; l[i] = 0.f;
    #pragma unroll
    for (int j = 0; j < 4; ++j) O[i][j] = 0.f;
  }
  for (int kt = 0; kt <= qi; ++kt) {
    int tokk = b * SS + kt * 64;
    __syncthreads();
    #pragma unroll
    for (int it = 0; it < 4; ++it) {
      int lin = it * 256 + tid;
      int r = lin >> 4, dq = (lin & 15) << 2;
      v4f kv = *(const v4f*)(k + (size_t)(tokk + r) * DD + cb + dq);
      KP[dq+0][r] = kv[0]; KP[dq+1][r] = kv[1]; KP[dq+2][r] = kv[2]; KP[dq+3][r] = kv[3];
      *(v4f*)&Vs[r][dq] = *(const v4f*)(v + (size_t)(tokk + r) * DD + cb + dq);
    }
    __syncthreads();
    float S[4][4] = {};
    #pragma unroll 8
    for (int kk = 0; kk < 64; ++kk) {
      v4f a = *(v4f*)&Qt[kk][r0];
      v4f bb = *(v4f*)&KP[kk][c0];
      #pragma unroll
      for (int i = 0; i < 4; ++i)
        #pragma unroll
        for (int j = 0; j < 4; ++j)
          S[i][j] = fmaf(a[i], bb[j], S[i][j]);
    }
    if (kt == qi) {
      #pragma unroll
      for (int i = 0; i < 4; ++i)
        #pragma unroll
        for (int j = 0; j < 4; ++j)
          if (c0 + j > r0 + i) S[i][j] = -1e30f;
    }
    #pragma unroll
    for (int i = 0; i < 4; ++i) {
      float tm = fmaxf(fmaxf(S[i][0], S[i][1]), fmaxf(S[i][2], S[i][3]));
      #pragma unroll
      for (int o = 8; o; o >>= 1) tm = fmaxf(tm, __shfl_xor(tm, o));
      float mn = fmaxf(m[i], tm);
      float fac = __expf(m[i] - mn);
      m[i] = mn;
      float ps = 0.f;
      #pragma unroll
      for (int j = 0; j < 4; ++j) { S[i][j] = __expf(S[i][j] - mn); ps += S[i][j]; }
      #pragma unroll
      for (int o = 8; o; o >>= 1) ps += __shfl_xor(ps, o);
      l[i] = l[i] * fac + ps;
      #pragma unroll
      for (int j = 0; j < 4; ++j) O[i][j] *= fac;
    }
    __syncthreads();                     // done reading KP as K
    #pragma unroll
    for (int i = 0; i < 4; ++i)
      #pragma unroll
      for (int j = 0; j < 4; ++j)
        KP[c0 + j][r0 + i] = S[i][j];    // Pt[k][row]
    __syncthreads();
    #pragma unroll 8
    for (int kk = 0; kk < 64; ++kk) {
      v4f p = *(v4f*)&KP[kk][r0];
      v4f vv = *(v4f*)&Vs[kk][c0];
      #pragma unroll
      for (int i = 0; i < 4; ++i)
        #pragma unroll
        for (int j = 0; j < 4; ++j)
          O[i][j] = fmaf(p[i], vv[j], O[i][j]);
    }
  }
  #pragma unroll
  for (int i = 0; i < 4; ++i) {
    float inv = 1.0f / l[i];
    v4f o;
    o[0] = O[i][0]*inv; o[1] = O[i][1]*inv; o[2] = O[i][2]*inv; o[3] = O[i][3]*inv;
    *(v4f*)(aout + (size_t)(tokq + r0 + i) * DD + cb + c0) = o;
  }
}

// ---------------- transpose + cast fp32 -> bf16: out[z][c][r] = in[z][r][c] ----------------
__global__ __launch_bounds__(256) void k_tcast(
    const float* __restrict__ in, ushort* __restrict__ out, int R, int C) {
  __shared__ float tile[32][33];
  size_t zoff = (size_t)blockIdx.z * R * C;
  int bx = blockIdx.x * 32, by = blockIdx.y * 32;
  int tx = threadIdx.x & 31, ty = threadIdx.x >> 5;
  #pragma unroll
  for (int i = 0; i < 32; i += 8)
    tile[ty + i][tx] = in[zoff + (size_t)(by + ty + i) * C + bx + tx];
  __syncthreads();
  #pragma unroll
  for (int i = 0; i < 32; i += 8)
    out[zoff + (size_t)(bx + ty + i) * R + by + tx] = f2bf(tile[tx][ty + i]);
}

// ---------------- gating: one wave per token ----------------
__global__ __launch_bounds__(256) void k_gate(
    const float* __restrict__ post, const float* __restrict__ gw,
    float* __restrict__ comb, float* __restrict__ probs, int* __restrict__ sel) {
  int t = blockIdx.x * 4 + (threadIdx.x >> 6);
  int lane = threadIdx.x & 63;
  float acc[8] = {};
  const float* xr = post + (size_t)t * DD;
  for (int it = 0; it < 16; ++it) {
    int d = it * 64 + lane;
    float xd = xr[d];
    v4f g0 = *(const v4f*)(gw + d * 8);
    v4f g1 = *(const v4f*)(gw + d * 8 + 4);
    acc[0] = fmaf(xd, g0[0], acc[0]); acc[1] = fmaf(xd, g0[1], acc[1]);
    acc[2] = fmaf(xd, g0[2], acc[2]); acc[3] = fmaf(xd, g0[3], acc[3]);
    acc[4] = fmaf(xd, g1[0], acc[4]); acc[5] = fmaf(xd, g1[1], acc[5]);
    acc[6] = fmaf(xd, g1[2], acc[6]); acc[7] = fmaf(xd, g1[3], acc[7]);
  }
  #pragma unroll
  for (int e = 0; e < 8; ++e) {
    float s = acc[e];
    #pragma unroll
    for (int o = 32; o; o >>= 1) s += __shfl_down(s, o);
    acc[e] = s;
  }
  if (lane == 0) {
    float mx = acc[0];
    #pragma unroll
    for (int e = 1; e < 8; ++e) mx = fmaxf(mx, acc[e]);
    float p[8], sum = 0.f;
    #pragma unroll
    for (int e = 0; e < 8; ++e) { p[e] = __expf(acc[e] - mx); sum += p[e]; }
    float inv = 1.f / sum;
    #pragma unroll
    for (int e = 0; e < 8; ++e) p[e] *= inv;
    // top-2 on logits (ties -> lower index, matches top_k)
    int e1 = 0; float l1 = acc[0];
    for (int e = 1; e < 8; ++e) if (acc[e] > l1) { l1 = acc[e]; e1 = e; }
    int e2 = -1; float l2 = -1e38f;
    for (int e = 0; e < 8; ++e) if (e != e1 && acc[e] > l2) { l2 = acc[e]; e2 = e; }
    float v1 = p[e1], v2 = p[e2];
    float s2 = 1.f / (v1 + v2);
    for (int e = 0; e < 8; ++e) {
      probs[t * 8 + e] = p[e];
      comb[t * 8 + e] = (e == e1) ? v1 * s2 : (e == e2) ? v2 * s2 : 0.f;
    }
    sel[t] = e1 * 8 + e2;
  }
}

// ---------------- aux loss: deterministic single-block reduce ----------------
__global__ __launch_bounds__(256) void k_aux(
    const float* __restrict__ probs, const int* __restrict__ sel,
    float* __restrict__ auxout) {
  int tid = threadIdx.x;
  float ps[8] = {}, cs[8] = {};
  for (int t = tid; t < NT; t += 256) {
    #pragma unroll
    for (int e = 0; e < 8; ++e) ps[e] += probs[t * 8 + e];
    int s = sel[t];
    cs[s >> 3] += 1.f; cs[s & 7] += 1.f;
  }
  __shared__ float red[4];
  __shared__ float tot[16];
  #pragma unroll
  for (int vv = 0; vv < 16; ++vv) {
    float s = (vv < 8) ? ps[vv] : cs[vv - 8];
    #pragma unroll
    for (int o = 32; o; o >>= 1) s += __shfl_down(s, o);
    __syncthreads();
    if ((tid & 63) == 0) red[tid >> 6] = s;
    __syncthreads();
    if (tid == 0) tot[vv] = red[0] + red[1] + red[2] + red[3];
  }
  __syncthreads();
  if (tid == 0) {
    float aux = 0.f;
    for (int e = 0; e < 8; ++e)
      aux += (tot[8 + e] * (1.f / NT)) * (tot[e] * (1.f / NT));
    auxout[0] = 8.f * aux;
  }
}

// ---------------- bf16 MFMA GEMM: C = A[M,K] @ Bt[N,K]^T ----------------
// 128x64 tile, BK=32, 4 waves (2x2), wave tile 64x32, mfma_f32_16x16x32_bf16.
// MODE 0: hb = bf16(relu(C)).  MODE 1: outp = addin + comb[row*8+e] * C.
template<int MODE>
__global__ __launch_bounds__(256) void k_gemm_bf16(
    const ushort* __restrict__ A, const ushort* __restrict__ Bt,
    ushort* __restrict__ hb, float* __restrict__ outp,
    const float* __restrict__ addin, const float* __restrict__ comb,
    int e, int N, int K) {
  __shared__ ushort lA[128 * 32];
  __shared__ ushort lB[64 * 32];
  int tid = threadIdx.x;
  int l = tid & 63, wid = tid >> 6;
  int wm = wid >> 1, wn = wid & 1;
  int m0 = blockIdx.x * 128, n0 = blockIdx.y * 64;
  fx4 zero = {0.f, 0.f, 0.f, 0.f};
  fx4 acc[4][2];
  #pragma unroll
  for (int mt = 0; mt < 4; ++mt)
    #pragma unroll
    for (int nt = 0; nt < 2; ++nt) acc[mt][nt] = zero;
  int sr = tid >> 2, sc = (tid & 3) << 3;   // staging: row, col(8-elem chunk)
  for (int kt = 0; kt < K; kt += 32) {
    bfx8 a0 = *(const bfx8*)(A + (size_t)(m0 + sr) * K + kt + sc);
    bfx8 a1 = *(const bfx8*)(A + (size_t)(m0 + sr + 64) * K + kt + sc);
    bfx8 b0 = *(const bfx8*)(Bt + (size_t)(n0 + sr) * K + kt + sc);
    __syncthreads();
    *(bfx8*)((char*)lA + sr * 64 + ((sc * 2) ^ ((sr & 3) << 4))) = a0;
    *(bfx8*)((char*)lA + (sr + 64) * 64 + ((sc * 2) ^ (((sr + 64) & 3) << 4))) = a1;
    *(bfx8*)((char*)lB + sr * 64 + ((sc * 2) ^ ((sr & 3) << 4))) = b0;
    __syncthreads();
    int kb = (l >> 4) << 4;   // byte offset of this lane's k-slice
    bfx8 af[4], bfr[2];
    #pragma unroll
    for (int mt = 0; mt < 4; ++mt) {
      int row = wm * 64 + mt * 16 + (l & 15);
      af[mt] = *(bfx8*)((char*)lA + row * 64 + (kb ^ ((row & 3) << 4)));
    }
    #pragma unroll
    for (int nt = 0; nt < 2; ++nt) {
      int row = wn * 32 + nt * 16 + (l & 15);
      bfr[nt] = *(bfx8*)((char*)lB + row * 64 + (kb ^ ((row & 3) << 4)));
    }
    #pragma unroll
    for (int mt = 0; mt < 4; ++mt)
      #pragma unroll
      for (int nt = 0; nt < 2; ++nt)
        acc[mt][nt] = __builtin_amdgcn_mfma_f32_16x16x32_bf16(af[mt], bfr[nt], acc[mt][nt], 0, 0, 0);
  }
  #pragma unroll
  for (int mt = 0; mt < 4; ++mt)
    #pragma unroll
    for (int nt = 0; nt < 2; ++nt)
      #pragma unroll
      for (int r = 0; r < 4; ++r) {
        int row = m0 + wm * 64 + mt * 16 + ((l >> 4) << 2) + r;
        int col = n0 + wn * 32 + nt * 16 + (l & 15);
        float vv = acc[mt][nt][r];
        if (MODE == 0) {
          hb[(size_t)row * N + col] = f2bf(fmaxf(vv, 0.f));
        } else {
          size_t idx = (size_t)row * N + col;
          outp[idx] = addin[idx] + comb[row * 8 + e] * vv;
        }
      }
}

extern "C" void kernel_launch(void* const* d_in, const int* in_sizes, int n_in,
                              void* d_out, int out_size, void* d_ws, size_t ws_size,
                              hipStream_t stream) {
  (void)in_sizes; (void)n_in; (void)out_size; (void)ws_size;
  const float* x     = (const float*)d_in[0];
  const float* wpre  = (const float*)d_in[1];
  const float* wpost = (const float*)d_in[2];
  const float* Wq    = (const float*)d_in[3];
  const float* Wk    = (const float*)d_in[4];
  const float* Wv    = (const float*)d_in[5];
  const float* Wo    = (const float*)d_in[6];
  const float* gw    = (const float*)d_in[7];
  const float* W1    = (const float*)d_in[8];
  const float* W2    = (const float*)d_in[9];
  float* out = (float*)d_out;
  char* ws = (char*)d_ws;
  const size_t MB = 1ull << 20;
  float*  pre  = (float*)(ws + 0 * MB);    // 16MB; reused as attn_out
  float*  qb   = (float*)(ws + 16 * MB);   // 16MB; reused as post_f32
  float*  kb   = (float*)(ws + 32 * MB);   // 16MB; reused as post_bf16
  float*  vb   = (float*)(ws + 48 * MB);   // 16MB; reused as h (bf16)
  float*  psum = (float*)(ws + 64 * MB);   // 16MB post_sum
  ushort* W1t  = (ushort*)(ws + 80 * MB);  // 16MB
  ushort* W2t  = (ushort*)(ws + 96 * MB);  // 16MB
  float*  comb  = (float*)(ws + 112 * MB);
  float*  probs = (float*)(ws + 112 * MB + (128u << 10));
  int*    sel   = (int*)(ws + 112 * MB + (256u << 10));

  // pre-norm (fp32)
  k_rmsnorm<<<NT, 256, 0, stream>>>(x, wpre, pre, nullptr);
  // QKV (fp32, fused z=3)
  k_gemm_f32<0><<<dim3(64, 16, 3), 256, 0, stream>>>(
      pre, Wq, Wk, Wv, qb, kb, vb, nullptr, NT, DD, DD);
  // flash attention (fp32) -> attn_out in `pre`
  k_attn<<<dim3(32, 32), 256, 0, stream>>>(qb, kb, vb, pre);
  // Wo + residual -> post_sum
  k_gemm_f32<1><<<dim3(64, 16, 1), 256, 0, stream>>>(
      pre, Wo, nullptr, nullptr, psum, nullptr, nullptr, x, NT, DD, DD);
  // post-norm: fp32 (gating) + bf16 (MoE A-operand)
  float* postf = qb;
  ushort* postb = (ushort*)kb;
  k_rmsnorm<<<NT, 256, 0, stream>>>(psum, wpost, postf, postb);
  // expert weights -> bf16 transposed
  k_tcast<<<dim3(32, 32, 8), 256, 0, stream>>>(W1, W1t, DD, DD);
  k_tcast<<<dim3(32, 32, 8), 256, 0, stream>>>(W2, W2t, DD, DD);
  // gating (fp32, exact top-k path)
  k_gate<<<NT / 4, 256, 0, stream>>>(postf, gw, comb, probs, sel);
  // dense MoE in bf16 MFMA: out = post_sum + sum_e comb_e * (relu(post@W1_e) @ W2_e)
  ushort* hb = (ushort*)vb;
  for (int e = 0; e < 8; ++e) {
    k_gemm_bf16<0><<<dim3(32, 16), 256, 0, stream>>>(
        postb, W1t + (size_t)e * DD * DD, hb, nullptr, nullptr, nullptr, e, DD, DD);
    k_gemm_bf16<1><<<dim3(32, 16), 256, 0, stream>>>(
        hb, W2t + (size_t)e * DD * DD, nullptr, out, e ? (const float*)out : psum, comb, e, DD, DD);
  }
  // aux loss scalar
  k_aux<<<1, 256, 0, stream>>>(probs, sel, out + 4194304);
}

// Round 2
// 1179.529 us; speedup vs baseline: 1.2049x; 1.2049x over previous
//
#include <hip/hip_runtime.h>
#include <hip/hip_bf16.h>

#define DD 1024
#define NHD 64
#define NHEAD 16
#define NE 8
#define NT 4096
#define SS 2048

typedef float v4f __attribute__((ext_vector_type(4)));
typedef short bfx8 __attribute__((ext_vector_type(8)));
typedef float fx4 __attribute__((ext_vector_type(4)));

__device__ inline ushort f2bf(float f) {
  union { float f; unsigned u; } x; x.f = f;
  unsigned r = (x.u + 0x7FFFu + ((x.u >> 16) & 1u)) >> 16;
  return (ushort)r;
}

// ---------------- RMSNorm: one block per row ----------------
__global__ __launch_bounds__(256) void k_rmsnorm(
    const float* __restrict__ x, const float* __restrict__ w,
    float* __restrict__ of32, ushort* __restrict__ obf) {
  int row = blockIdx.x;
  int tid = threadIdx.x;
  v4f v = *(const v4f*)(x + (size_t)row * DD + tid * 4);
  float ss = v[0]*v[0] + v[1]*v[1] + v[2]*v[2] + v[3]*v[3];
  #pragma unroll
  for (int o = 32; o; o >>= 1) ss += __shfl_down(ss, o);
  __shared__ float red[4];
  if ((tid & 63) == 0) red[tid >> 6] = ss;
  __syncthreads();
  float tot = red[0] + red[1] + red[2] + red[3];
  float sc = rsqrtf(tot * (1.0f / DD) + 1e-5f);
  v4f wv = *(const v4f*)(w + tid * 4);
  v4f o;
  o[0] = v[0]*sc*wv[0]; o[1] = v[1]*sc*wv[1];
  o[2] = v[2]*sc*wv[2]; o[3] = v[3]*sc*wv[3];
  if (of32) *(v4f*)(of32 + (size_t)row * DD + tid * 4) = o;
  if (obf) {
    ushort4 ub;
    ub.x = f2bf(o[0]); ub.y = f2bf(o[1]); ub.z = f2bf(o[2]); ub.w = f2bf(o[3]);
    *(ushort4*)(obf + (size_t)row * DD + tid * 4) = ub;
  }
}

// ---------------- fp32 GEMM: C = A[M,K] @ B[K,N] (B row-major) ----------------
// 128x64 tile, BK=32, 256 threads, 8x4 per thread. Swizzled A tile, reg prefetch.
// MODE 0: z-select among (B0,C0)/(B1,C1)/(B2,C2).  MODE 1: C0 = A@B0 + resid.
template<int MODE>
__global__ __launch_bounds__(256) void k_gemm_f32(
    const float* __restrict__ A,
    const float* __restrict__ B0, const float* __restrict__ B1, const float* __restrict__ B2,
    float* __restrict__ C0, float* __restrict__ C1, float* __restrict__ C2,
    const float* __restrict__ resid, int M, int N, int K) {
  const float* B = (blockIdx.z == 0) ? B0 : (blockIdx.z == 1) ? B1 : B2;
  float* C = (blockIdx.z == 0) ? C0 : (blockIdx.z == 1) ? C1 : C2;
  __shared__ float As[128][32];   // row-major, col granule swizzled by ((r>>2)&7)<<2
  __shared__ float Bs[32][64];    // row-major (k-major), plain
  int tid = threadIdx.x;
  int m0 = blockIdx.x * 128, n0 = blockIdx.y * 64;
  int r0 = (tid >> 4) << 3, c0 = (tid & 15) << 2;
  float acc[8][4] = {};
  // staging assignments
  int asr = tid >> 3, akc = (tid & 7) << 2;     // A: rows (4 chunks of 32), 8 k-granules
  int bsr = tid >> 4, bnc = (tid & 15) << 2;    // B: rows (2 chunks of 16), 16 n-granules
  v4f ald[4], bld[2];
  #pragma unroll
  for (int pc = 0; pc < 4; ++pc)
    ald[pc] = *(const v4f*)(A + (size_t)(m0 + pc * 32 + asr) * K + akc);
  #pragma unroll
  for (int pc = 0; pc < 2; ++pc)
    bld[pc] = *(const v4f*)(B + (size_t)(pc * 16 + bsr) * N + n0 + bnc);
  for (int kt = 0; kt < K; kt += 32) {
    __syncthreads();
    #pragma unroll
    for (int pc = 0; pc < 4; ++pc) {
      int r = pc * 32 + asr;
      *(v4f*)&As[r][akc ^ (((r >> 2) & 7) << 2)] = ald[pc];
    }
    #pragma unroll
    for (int pc = 0; pc < 2; ++pc)
      *(v4f*)&Bs[pc * 16 + bsr][bnc] = bld[pc];
    if (kt + 32 < K) {
      #pragma unroll
      for (int pc = 0; pc < 4; ++pc)
        ald[pc] = *(const v4f*)(A + (size_t)(m0 + pc * 32 + asr) * K + kt + 32 + akc);
      #pragma unroll
      for (int pc = 0; pc < 2; ++pc)
        bld[pc] = *(const v4f*)(B + (size_t)(kt + 32 + pc * 16 + bsr) * N + n0 + bnc);
    }
    __syncthreads();
    #pragma unroll
    for (int kq = 0; kq < 32; kq += 4) {
      v4f av[8], bv[4];
      #pragma unroll
      for (int i = 0; i < 8; ++i)
        av[i] = *(v4f*)&As[r0 + i][kq ^ ((((r0 + i) >> 2) & 7) << 2)];
      #pragma unroll
      for (int x = 0; x < 4; ++x)
        bv[x] = *(v4f*)&Bs[kq + x][c0];
      #pragma unroll
      for (int i = 0; i < 8; ++i)
        #pragma unroll
        for (int x = 0; x < 4; ++x)
          #pragma unroll
          for (int j = 0; j < 4; ++j)
            acc[i][j] = fmaf(av[i][x], bv[x][j], acc[i][j]);
    }
  }
  #pragma unroll
  for (int i = 0; i < 8; ++i) {
    size_t idx = (size_t)(m0 + r0 + i) * N + n0 + c0;
    v4f o;
    o[0] = acc[i][0]; o[1] = acc[i][1]; o[2] = acc[i][2]; o[3] = acc[i][3];
    if (MODE == 1) {
      v4f rz = *(const v4f*)(resid + idx);
      o[0] += rz[0]; o[1] += rz[1]; o[2] += rz[2]; o[3] += rz[3];
    }
    *(v4f*)(C + idx) = o;
  }
}

// ---------------- fp32 flash attention (causal), pair-balanced ----------------
// block = pair of q-tiles (p, 31-p) x (b,h): exactly 33 tile-iters per block.
// Row-major swizzled LDS, reg prefetch of K/V, 3 barriers/iter.
__global__ __launch_bounds__(256) void k_attn(
    const float* __restrict__ q, const float* __restrict__ k,
    const float* __restrict__ v, float* __restrict__ aout) {
  __shared__ float Qs[64][64];   // [row][d^swz]  (pre-scaled by 0.125)
  __shared__ float Ks[64][64];   // [row][d^swz]
  __shared__ float Ps[64][64];   // [qrow][k^swz]
  __shared__ float Vs[64][64];   // [k][d] plain
  int p = blockIdx.x;            // 0..15
  int bh = blockIdx.y;
  int b = bh >> 4, h = bh & 15;
  int cb = h * NHD;
  int tid = threadIdx.x;
  int r0 = (tid >> 4) << 2, c0 = (tid & 15) << 2;
  int swzQ = ((r0 >> 2) & 7) << 2;       // rows r0..r0+3 share r0>>2
  int swzK = ((c0 >> 2) & 7) << 2;       // rows c0..c0+3 share c0>>2
  int sr = tid >> 4, sc = (tid & 15) << 2;   // staging: 4 chunks of 16 rows
  #pragma unroll
  for (int half = 0; half < 2; ++half) {
    int qi = (half == 0) ? (31 - p) : p;
    int q0 = qi * 64;
    int tokq = b * SS + q0;
    v4f qld[4], kld[4], vld[4];
    #pragma unroll
    for (int pc = 0; pc < 4; ++pc) {
      int r = pc * 16 + sr;
      qld[pc] = *(const v4f*)(q + (size_t)(tokq + r) * DD + cb + sc);
      kld[pc] = *(const v4f*)(k + (size_t)(b * SS + r) * DD + cb + sc);
      vld[pc] = *(const v4f*)(v + (size_t)(b * SS + r) * DD + cb + sc);
    }
    float mrow[4], lrow[4], O[4][4];
    #pragma unroll
    for (int i = 0; i < 4; ++i) {
      mrow[i] = -1e30f; lrow[i] = 0.f;
      #pragma unroll
      for (int j = 0; j < 4; ++j) O[i][j] = 0.f;
    }
    for (int kt = 0; kt <= qi; ++kt) {
      __syncthreads();   // prev readers of Ks/Vs/Ps (and Qs at tile switch) done
      #pragma unroll
      for (int pc = 0; pc < 4; ++pc) {
        int r = pc * 16 + sr;
        int cw = sc ^ (((r >> 2) & 7) << 2);
        if (kt == 0) {
          v4f qs = qld[pc];
          qs[0] *= 0.125f; qs[1] *= 0.125f; qs[2] *= 0.125f; qs[3] *= 0.125f;
          *(v4f*)&Qs[r][cw] = qs;
        }
        *(v4f*)&Ks[r][cw] = kld[pc];
        *(v4f*)&Vs[r][sc] = vld[pc];
      }
      if (kt < qi) {
        int tokk = b * SS + (kt + 1) * 64;
        #pragma unroll
        for (int pc = 0; pc < 4; ++pc) {
          int r = pc * 16 + sr;
          kld[pc] = *(const v4f*)(k + (size_t)(tokk + r) * DD + cb + sc);
          vld[pc] = *(const v4f*)(v + (size_t)(tokk + r) * DD + cb + sc);
        }
      }
      __syncthreads();   // tiles ready
      float S[4][4] = {};
      #pragma unroll
      for (int dq = 0; dq < 64; dq += 4) {
        v4f qv[4], kv[4];
        #pragma unroll
        for (int i = 0; i < 4; ++i) qv[i] = *(v4f*)&Qs[r0 + i][dq ^ swzQ];
        #pragma unroll
        for (int j = 0; j < 4; ++j) kv[j] = *(v4f*)&Ks[c0 + j][dq ^ swzK];
        #pragma unroll
        for (int i = 0; i < 4; ++i)
          #pragma unroll
          for (int x = 0; x < 4; ++x)
            #pragma unroll
            for (int j = 0; j < 4; ++j)
              S[i][j] = fmaf(qv[i][x], kv[j][x], S[i][j]);
      }
      if (kt == qi) {
        #pragma unroll
        for (int i = 0; i < 4; ++i)
          #pragma unroll
          for (int j = 0; j < 4; ++j)
            if (c0 + j > r0 + i) S[i][j] = -1e30f;
      }
      #pragma unroll
      for (int i = 0; i < 4; ++i) {
        float tm = fmaxf(fmaxf(S[i][0], S[i][1]), fmaxf(S[i][2], S[i][3]));
        #pragma unroll
        for (int o = 8; o; o >>= 1) tm = fmaxf(tm, __shfl_xor(tm, o));
        float mn = fmaxf(mrow[i], tm);
        float fac = __expf(mrow[i] - mn);
        mrow[i] = mn;
        float ps = 0.f;
        #pragma unroll
        for (int j = 0; j < 4; ++j) { S[i][j] = __expf(S[i][j] - mn); ps += S[i][j]; }
        #pragma unroll
        for (int o = 8; o; o >>= 1) ps += __shfl_xor(ps, o);
        lrow[i] = lrow[i] * fac + ps;
        #pragma unroll
        for (int j = 0; j < 4; ++j) O[i][j] *= fac;
      }
      #pragma unroll
      for (int i = 0; i < 4; ++i) {
        v4f pw;
        pw[0] = S[i][0]; pw[1] = S[i][1]; pw[2] = S[i][2]; pw[3] = S[i][3];
        *(v4f*)&Ps[r0 + i][c0 ^ swzQ] = pw;
      }
      __syncthreads();   // Ps ready
      #pragma unroll
      for (int kq = 0; kq < 64; kq += 4) {
        v4f pr[4], vr[4];
        #pragma unroll
        for (int i = 0; i < 4; ++i) pr[i] = *(v4f*)&Ps[r0 + i][kq ^ swzQ];
        #pragma unroll
        for (int x = 0; x < 4; ++x) vr[x] = *(v4f*)&Vs[kq + x][c0];
        #pragma unroll
        for (int i = 0; i < 4; ++i)
          #pragma unroll
          for (int x = 0; x < 4; ++x)
            #pragma unroll
            for (int j = 0; j < 4; ++j)
              O[i][j] = fmaf(pr[i][x], vr[x][j], O[i][j]);
      }
    }
    #pragma unroll
    for (int i = 0; i < 4; ++i) {
      float inv = 1.0f / lrow[i];
      v4f o;
      o[0] = O[i][0]*inv; o[1] = O[i][1]*inv; o[2] = O[i][2]*inv; o[3] = O[i][3]*inv;
      *(v4f*)(aout + (size_t)(tokq + r0 + i) * DD + cb + c0) = o;
    }
  }
}

// ---------------- transpose + cast fp32 -> bf16: out[z][c][r] = in[z][r][c] ----------------
__global__ __launch_bounds__(256) void k_tcast(
    const float* __restrict__ in, ushort* __restrict__ out, int R, int C) {
  __shared__ float tile[32][33];
  size_t zoff = (size_t)blockIdx.z * R * C;
  int bx = blockIdx.x * 32, by = blockIdx.y * 32;
  int tx = threadIdx.x & 31, ty = threadIdx.x >> 5;
  #pragma unroll
  for (int i = 0; i < 32; i += 8)
    tile[ty + i][tx] = in[zoff + (size_t)(by + ty + i) * C + bx + tx];
  __syncthreads();
  #pragma unroll
  for (int i = 0; i < 32; i += 8)
    out[zoff + (size_t)(bx + ty + i) * R + by + tx] = f2bf(tile[tx][ty + i]);
}

// ---------------- gating: one wave per token ----------------
__global__ __launch_bounds__(256) void k_gate(
    const float* __restrict__ post, const float* __restrict__ gw,
    float* __restrict__ comb, float* __restrict__ probs, int* __restrict__ sel) {
  int t = blockIdx.x * 4 + (threadIdx.x >> 6);
  int lane = threadIdx.x & 63;
  float acc[8] = {};
  const float* xr = post + (size_t)t * DD;
  for (int it = 0; it < 16; ++it) {
    int d = it * 64 + lane;
    float xd = xr[d];
    v4f g0 = *(const v4f*)(gw + d * 8);
    v4f g1 = *(const v4f*)(gw + d * 8 + 4);
    acc[0] = fmaf(xd, g0[0], acc[0]); acc[1] = fmaf(xd, g0[1], acc[1]);
    acc[2] = fmaf(xd, g0[2], acc[2]); acc[3] = fmaf(xd, g0[3], acc[3]);
    acc[4] = fmaf(xd, g1[0], acc[4]); acc[5] = fmaf(xd, g1[1], acc[5]);
    acc[6] = fmaf(xd, g1[2], acc[6]); acc[7] = fmaf(xd, g1[3], acc[7]);
  }
  #pragma unroll
  for (int e = 0; e < 8; ++e) {
    float s = acc[e];
    #pragma unroll
    for (int o = 32; o; o >>= 1) s += __shfl_down(s, o);
    acc[e] = s;
  }
  if (lane == 0) {
    float mx = acc[0];
    #pragma unroll
    for (int e = 1; e < 8; ++e) mx = fmaxf(mx, acc[e]);
    float p[8], sum = 0.f;
    #pragma unroll
    for (int e = 0; e < 8; ++e) { p[e] = __expf(acc[e] - mx); sum += p[e]; }
    float inv = 1.f / sum;
    #pragma unroll
    for (int e = 0; e < 8; ++e) p[e] *= inv;
    int e1 = 0; float l1 = acc[0];
    for (int e = 1; e < 8; ++e) if (acc[e] > l1) { l1 = acc[e]; e1 = e; }
    int e2 = -1; float l2 = -1e38f;
    for (int e = 0; e < 8; ++e) if (e != e1 && acc[e] > l2) { l2 = acc[e]; e2 = e; }
    float v1 = p[e1], v2 = p[e2];
    float s2 = 1.f / (v1 + v2);
    for (int e = 0; e < 8; ++e) {
      probs[t * 8 + e] = p[e];
      comb[t * 8 + e] = (e == e1) ? v1 * s2 : (e == e2) ? v2 * s2 : 0.f;
    }
    sel[t] = e1 * 8 + e2;
  }
}

// ---------------- aux loss: deterministic single-block reduce ----------------
__global__ __launch_bounds__(256) void k_aux(
    const float* __restrict__ probs, const int* __restrict__ sel,
    float* __restrict__ auxout) {
  int tid = threadIdx.x;
  float ps[8] = {}, cs[8] = {};
  for (int t = tid; t < NT; t += 256) {
    #pragma unroll
    for (int e = 0; e < 8; ++e) ps[e] += probs[t * 8 + e];
    int s = sel[t];
    cs[s >> 3] += 1.f; cs[s & 7] += 1.f;
  }
  __shared__ float red[4];
  __shared__ float tot[16];
  #pragma unroll
  for (int vv = 0; vv < 16; ++vv) {
    float s = (vv < 8) ? ps[vv] : cs[vv - 8];
    #pragma unroll
    for (int o = 32; o; o >>= 1) s += __shfl_down(s, o);
    __syncthreads();
    if ((tid & 63) == 0) red[tid >> 6] = s;
    __syncthreads();
    if (tid == 0) tot[vv] = red[0] + red[1] + red[2] + red[3];
  }
  __syncthreads();
  if (tid == 0) {
    float aux = 0.f;
    for (int e = 0; e < 8; ++e)
      aux += (tot[8 + e] * (1.f / NT)) * (tot[e] * (1.f / NT));
    auxout[0] = 8.f * aux;
  }
}

// ---------------- bf16 MFMA GEMM: C = A[M,K] @ Bt[N,K]^T ----------------
template<int MODE>
__global__ __launch_bounds__(256) void k_gemm_bf16(
    const ushort* __restrict__ A, const ushort* __restrict__ Bt,
    ushort* __restrict__ hb, float* __restrict__ outp,
    const float* __restrict__ addin, const float* __restrict__ comb,
    int e, int N, int K) {
  __shared__ ushort lA[128 * 32];
  __shared__ ushort lB[64 * 32];
  int tid = threadIdx.x;
  int l = tid & 63, wid = tid >> 6;
  int wm = wid >> 1, wn = wid & 1;
  int m0 = blockIdx.x * 128, n0 = blockIdx.y * 64;
  fx4 zero = {0.f, 0.f, 0.f, 0.f};
  fx4 acc[4][2];
  #pragma unroll
  for (int mt = 0; mt < 4; ++mt)
    #pragma unroll
    for (int nt = 0; nt < 2; ++nt) acc[mt][nt] = zero;
  int sr = tid >> 2, sc = (tid & 3) << 3;
  for (int kt = 0; kt < K; kt += 32) {
    bfx8 a0 = *(const bfx8*)(A + (size_t)(m0 + sr) * K + kt + sc);
    bfx8 a1 = *(const bfx8*)(A + (size_t)(m0 + sr + 64) * K + kt + sc);
    bfx8 b0 = *(const bfx8*)(Bt + (size_t)(n0 + sr) * K + kt + sc);
    __syncthreads();
    *(bfx8*)((char*)lA + sr * 64 + ((sc * 2) ^ ((sr & 3) << 4))) = a0;
    *(bfx8*)((char*)lA + (sr + 64) * 64 + ((sc * 2) ^ (((sr + 64) & 3) << 4))) = a1;
    *(bfx8*)((char*)lB + sr * 64 + ((sc * 2) ^ ((sr & 3) << 4))) = b0;
    __syncthreads();
    int kb = (l >> 4) << 4;
    bfx8 af[4], bfr[2];
    #pragma unroll
    for (int mt = 0; mt < 4; ++mt) {
      int row = wm * 64 + mt * 16 + (l & 15);
      af[mt] = *(bfx8*)((char*)lA + row * 64 + (kb ^ ((row & 3) << 4)));
    }
    #pragma unroll
    for (int nt = 0; nt < 2; ++nt) {
      int row = wn * 32 + nt * 16 + (l & 15);
      bfr[nt] = *(bfx8*)((char*)lB + row * 64 + (kb ^ ((row & 3) << 4)));
    }
    #pragma unroll
    for (int mt = 0; mt < 4; ++mt)
      #pragma unroll
      for (int nt = 0; nt < 2; ++nt)
        acc[mt][nt] = __builtin_amdgcn_mfma_f32_16x16x32_bf16(af[mt], bfr[nt], acc[mt][nt], 0, 0, 0);
  }
  #pragma unroll
  for (int mt = 0; mt < 4; ++mt)
    #pragma unroll
    for (int nt = 0; nt < 2; ++nt)
      #pragma unroll
      for (int r = 0; r < 4; ++r) {
        int row = m0 + wm * 64 + mt * 16 + ((l >> 4) << 2) + r;
        int col = n0 + wn * 32 + nt * 16 + (l & 15);
        float vv = acc[mt][nt][r];
        if (MODE == 0) {
          hb[(size_t)row * N + col] = f2bf(fmaxf(vv, 0.f));
        } else {
          size_t idx = (size_t)row * N + col;
          outp[idx] = addin[idx] + comb[row * 8 + e] * vv;
        }
      }
}

extern "C" void kernel_launch(void* const* d_in, const int* in_sizes, int n_in,
                              void* d_out, int out_size, void* d_ws, size_t ws_size,
                              hipStream_t stream) {
  (void)in_sizes; (void)n_in; (void)out_size; (void)ws_size;
  const float* x     = (const float*)d_in[0];
  const float* wpre  = (const float*)d_in[1];
  const float* wpost = (const float*)d_in[2];
  const float* Wq    = (const float*)d_in[3];
  const float* Wk    = (const float*)d_in[4];
  const float* Wv    = (const float*)d_in[5];
  const float* Wo    = (const float*)d_in[6];
  const float* gw    = (const float*)d_in[7];
  const float* W1    = (const float*)d_in[8];
  const float* W2    = (const float*)d_in[9];
  float* out = (float*)d_out;
  char* ws = (char*)d_ws;
  const size_t MB = 1ull << 20;
  float*  pre  = (float*)(ws + 0 * MB);    // 16MB; reused as attn_out
  float*  qb   = (float*)(ws + 16 * MB);   // 16MB; reused as post_f32
  float*  kb   = (float*)(ws + 32 * MB);   // 16MB; reused as post_bf16
  float*  vb   = (float*)(ws + 48 * MB);   // 16MB; reused as h (bf16)
  float*  psum = (float*)(ws + 64 * MB);   // 16MB post_sum
  ushort* W1t  = (ushort*)(ws + 80 * MB);  // 16MB
  ushort* W2t  = (ushort*)(ws + 96 * MB);  // 16MB
  float*  comb  = (float*)(ws + 112 * MB);
  float*  probs = (float*)(ws + 112 * MB + (128u << 10));
  int*    sel   = (int*)(ws + 112 * MB + (256u << 10));

  // pre-norm (fp32)
  k_rmsnorm<<<NT, 256, 0, stream>>>(x, wpre, pre, nullptr);
  // QKV (fp32, fused z=3)
  k_gemm_f32<0><<<dim3(32, 16, 3), 256, 0, stream>>>(
      pre, Wq, Wk, Wv, qb, kb, vb, nullptr, NT, DD, DD);
  // flash attention (fp32) -> attn_out in `pre`
  k_attn<<<dim3(16, 32), 256, 0, stream>>>(qb, kb, vb, pre);
  // Wo + residual -> post_sum
  k_gemm_f32<1><<<dim3(32, 16, 1), 256, 0, stream>>>(
      pre, Wo, nullptr, nullptr, psum, nullptr, nullptr, x, NT, DD, DD);
  // post-norm: fp32 (gating) + bf16 (MoE A-operand)
  float* postf = qb;
  ushort* postb = (ushort*)kb;
  k_rmsnorm<<<NT, 256, 0, stream>>>(psum, wpost, postf, postb);
  // expert weights -> bf16 transposed
  k_tcast<<<dim3(32, 32, 8), 256, 0, stream>>>(W1, W1t, DD, DD);
  k_tcast<<<dim3(32, 32, 8), 256, 0, stream>>>(W2, W2t, DD, DD);
  // gating (fp32, exact top-k path)
  k_gate<<<NT / 4, 256, 0, stream>>>(postf, gw, comb, probs, sel);
  // dense MoE in bf16 MFMA: out = post_sum + sum_e comb_e * (relu(post@W1_e) @ W2_e)
  ushort* hb = (ushort*)vb;
  for (int e = 0; e < 8; ++e) {
    k_gemm_bf16<0><<<dim3(32, 16), 256, 0, stream>>>(
        postb, W1t + (size_t)e * DD * DD, hb, nullptr, nullptr, nullptr, e, DD, DD);
    k_gemm_bf16<1><<<dim3(32, 16), 256, 0, stream>>>(
        hb, W2t + (size_t)e * DD * DD, nullptr, out, e ? (const float*)out : psum, comb, e, DD, DD);
  }
  // aux loss scalar
  k_aux<<<1, 256, 0, stream>>>(probs, sel, out + 4194304);
}